// Round 11
// baseline (2044.126 us; speedup 1.0000x reference)
//
#include <hip/hip_runtime.h>
#include <hip/hip_bf16.h>
#include <math.h>

typedef _Float16 half8 __attribute__((ext_vector_type(8)));
typedef float f32x4 __attribute__((ext_vector_type(4)));

// ---------------- prep: split W (KxN fp32) into hi/lo fp16, transposed to NxK ----------------
__global__ void split_transpose_kernel(const float* __restrict__ W,
                                       _Float16* __restrict__ WhT,
                                       _Float16* __restrict__ WlT,
                                       int K, int N) {
  int idx = blockIdx.x * 256 + threadIdx.x;
  if (idx >= K * N) return;
  int k = idx / N, n = idx - k * N;
  float w = W[idx];
  _Float16 h = (_Float16)w;
  float r = w - (float)h;               // exact
  _Float16 l = (_Float16)(r * 2048.0f); // scaled residual stays fp16-normal
  WhT[(size_t)n * K + k] = h;
  WlT[(size_t)n * K + k] = l;
}

// ---------------- GEMM1: h0pair = relu(x @ W0 + b0), fp16x3, LDS-FREE K-loop -----------------
// BM=128, BN=128, BK=32; 256 thr = 4 waves (2x2), per-wave 64x64.
// Every MFMA operand fragment is 8 k-contiguous elems/lane -> direct global loads (L2-hot).
// No LDS, no barriers in the K-loop. Depth-1 reg prefetch of A-raw + Bh; Bl issued at step
// start and covered by the convert + acc_h MFMA block.
__global__ __launch_bounds__(256, 2)
void gemm1_direct_kernel(const float* __restrict__ A32,
                         const _Float16* __restrict__ Bh,
                         const _Float16* __restrict__ Bl,
                         const float* __restrict__ bias,
                         _Float16* __restrict__ Ch,
                         _Float16* __restrict__ Cl,
                         int K, int N) {
  const int tid = threadIdx.x;
  const int lane = tid & 63;
  const int w = tid >> 6;          // wave 0..3; 2M x 2N
  const int wr = w >> 1, wc = w & 1;

  // 1-D grid, bijective XCD swizzle (gridDim.x % 8 == 0), N-tile fastest for L2 A-reuse
  const int cpx = gridDim.x >> 3;
  const int wg = (blockIdx.x & 7) * cpx + (blockIdx.x >> 3);
  const int ntiles = N >> 7;
  const int nT = wg % ntiles;
  const int mT = wg / ntiles;
  const long bm = (long)mT * 128;
  const long bn = (long)nT * 128;

  const int fr = lane & 15;
  const int kg = lane >> 4;        // 0..3, 8 k-elems each

  // 32-bit element offsets (saddr-form addressing: SGPR base + VGPR offset)
  unsigned oA[4], oB[4];
  #pragma unroll
  for (int m = 0; m < 4; ++m)
    oA[m] = (unsigned)((bm + (wr * 4 + m) * 16 + fr) * K + kg * 8);
  #pragma unroll
  for (int n = 0; n < 4; ++n)
    oB[n] = (unsigned)((bn + (wc * 4 + n) * 16 + fr) * K + kg * 8);

  f32x4 acc_h[4][4] = {};
  f32x4 acc_c[4][4] = {};

  // ---- prologue: prefetch step-0 A raw + Bh
  f32x4 ar0[4], ar1[4];
  half8 bhr[4];
  #pragma unroll
  for (int m = 0; m < 4; ++m) {
    ar0[m] = *(const f32x4*)(A32 + oA[m]);
    ar1[m] = *(const f32x4*)(A32 + oA[m] + 4);
  }
  #pragma unroll
  for (int n = 0; n < 4; ++n) bhr[n] = *(const half8*)(Bh + oB[n]);

  for (int kt = 0; kt < K; kt += 32) {
    const bool has_next = (kt + 32 < K);

    // 1. issue Bl(t) loads (consumed by second MFMA block — latency covered below)
    half8 bl[4];
    #pragma unroll
    for (int n = 0; n < 4; ++n) bl[n] = *(const half8*)(Bl + oB[n]);

    // 2. convert prefetched A raw -> hi/lo fp16 (VALU; covers Bl latency)
    half8 ah[4], al[4];
    #pragma unroll
    for (int m = 0; m < 4; ++m) {
      #pragma unroll
      for (int e = 0; e < 4; ++e) {
        float xv = ar0[m][e];
        _Float16 hv = (_Float16)xv;
        ah[m][e] = hv;
        al[m][e] = (_Float16)((xv - (float)hv) * 2048.0f);
        float yv = ar1[m][e];
        _Float16 hw = (_Float16)yv;
        ah[m][e + 4] = hw;
        al[m][e + 4] = (_Float16)((yv - (float)hw) * 2048.0f);
      }
    }

    // 3. take cur Bh; issue next-step prefetch (A raw + Bh)
    half8 bh[4];
    #pragma unroll
    for (int n = 0; n < 4; ++n) bh[n] = bhr[n];
    if (has_next) {
      #pragma unroll
      for (int m = 0; m < 4; ++m) {
        oA[m] += 32;
        ar0[m] = *(const f32x4*)(A32 + oA[m]);
        ar1[m] = *(const f32x4*)(A32 + oA[m] + 4);
      }
      #pragma unroll
      for (int n = 0; n < 4; ++n) {
        oB[n] += 32;
        bhr[n] = *(const half8*)(Bh + oB[n]);
      }
    }

    // 4. MFMA: 48 per wave; per-element order identical to R8 (h; ah*bl; al*bh)
    #pragma unroll
    for (int m = 0; m < 4; ++m)
      #pragma unroll
      for (int n = 0; n < 4; ++n)
        acc_h[m][n] = __builtin_amdgcn_mfma_f32_16x16x32_f16(ah[m], bh[n], acc_h[m][n], 0, 0, 0);
    #pragma unroll
    for (int m = 0; m < 4; ++m)
      #pragma unroll
      for (int n = 0; n < 4; ++n)
        acc_c[m][n] = __builtin_amdgcn_mfma_f32_16x16x32_f16(ah[m], bl[n], acc_c[m][n], 0, 0, 0);
    #pragma unroll
    for (int m = 0; m < 4; ++m)
      #pragma unroll
      for (int n = 0; n < 4; ++n)
        acc_c[m][n] = __builtin_amdgcn_mfma_f32_16x16x32_f16(al[m], bh[n], acc_c[m][n], 0, 0, 0);
  }

  // ---- epilogue: combine, bias, relu, split-store (R8-identical)
  const float inv2048 = 1.0f / 2048.0f;
  #pragma unroll
  for (int m = 0; m < 4; ++m) {
    #pragma unroll
    for (int n = 0; n < 4; ++n) {
      long col = bn + wc * 64 + n * 16 + (lane & 15);
      float bv = bias[col];
      long row0 = bm + wr * 64 + m * 16 + (lane >> 4) * 4;
      #pragma unroll
      for (int j = 0; j < 4; ++j) {
        float v = acc_h[m][n][j] + acc_c[m][n][j] * inv2048 + bv;
        v = fmaxf(v, 0.0f);
        size_t idx = (size_t)(row0 + j) * N + col;
        _Float16 hv = (_Float16)v;
        Ch[idx] = hv;
        Cl[idx] = (_Float16)((v - (float)hv) * 2048.0f);
      }
    }
  }
}

// ---------------- fp64 polar: Q = U Vh of 3x3 R via Jacobi eigen of R^T R + GS ----------------
__device__ __forceinline__ void polar3x3(const double R[3][3], double Q[3][3]) {
  double S[3][3], V[3][3];
  #pragma unroll
  for (int i = 0; i < 3; ++i) {
    #pragma unroll
    for (int j = 0; j < 3; ++j) {
      S[i][j] = R[0][i] * R[0][j] + R[1][i] * R[1][j] + R[2][i] * R[2][j];
      V[i][j] = (i == j) ? 1.0 : 0.0;
    }
  }

#define JROT(p, q, rr)                                                        \
  {                                                                           \
    double apq = S[p][q];                                                     \
    if (fabs(apq) > 1e-300) {                                                 \
      double tau = (S[q][q] - S[p][p]) / (2.0 * apq);                         \
      double t = copysign(1.0, tau) / (fabs(tau) + sqrt(1.0 + tau * tau));    \
      double c = 1.0 / sqrt(1.0 + t * t);                                     \
      double s = t * c;                                                       \
      S[p][p] -= t * apq;                                                     \
      S[q][q] += t * apq;                                                     \
      S[p][q] = 0.0; S[q][p] = 0.0;                                           \
      double srp = c * S[rr][p] - s * S[rr][q];                               \
      double srq = s * S[rr][p] + c * S[rr][q];                               \
      S[rr][p] = srp; S[p][rr] = srp; S[rr][q] = srq; S[q][rr] = srq;         \
      _Pragma("unroll")                                                       \
      for (int i = 0; i < 3; ++i) {                                           \
        double vip = V[i][p], viq = V[i][q];                                  \
        V[i][p] = c * vip - s * viq;                                          \
        V[i][q] = s * vip + c * viq;                                          \
      }                                                                       \
    }                                                                         \
  }

  #pragma unroll 1
  for (int sweep = 0; sweep < 6; ++sweep) {
    JROT(0, 1, 2)
    JROT(0, 2, 1)
    JROT(1, 2, 0)
  }
#undef JROT

  double l0 = S[0][0], l1 = S[1][1], l2 = S[2][2];
  double v0[3] = {V[0][0], V[1][0], V[2][0]};
  double v1[3] = {V[0][1], V[1][1], V[2][1]};
  double v2[3] = {V[0][2], V[1][2], V[2][2]};

#define CSWAPV(la, lb, va, vb)                                                \
  if (la < lb) {                                                              \
    double tt = la; la = lb; lb = tt;                                         \
    _Pragma("unroll")                                                         \
    for (int i = 0; i < 3; ++i) { double tv = va[i]; va[i] = vb[i]; vb[i] = tv; } \
  }
  CSWAPV(l0, l1, v0, v1)
  CSWAPV(l0, l2, v0, v2)
  CSWAPV(l1, l2, v1, v2)
#undef CSWAPV

  double w0[3], w1[3], w2[3];
  #pragma unroll
  for (int i = 0; i < 3; ++i) {
    w0[i] = R[i][0] * v0[0] + R[i][1] * v0[1] + R[i][2] * v0[2];
    w1[i] = R[i][0] * v1[0] + R[i][1] * v1[1] + R[i][2] * v1[2];
    w2[i] = R[i][0] * v2[0] + R[i][1] * v2[1] + R[i][2] * v2[2];
  }

  double n0 = sqrt(w0[0]*w0[0] + w0[1]*w0[1] + w0[2]*w0[2]);
  double u0[3];
  if (n0 > 1e-150) {
    double r0 = 1.0 / n0;
    u0[0] = w0[0]*r0; u0[1] = w0[1]*r0; u0[2] = w0[2]*r0;
  } else { u0[0] = 1.0; u0[1] = 0.0; u0[2] = 0.0; }

  double d01 = u0[0]*w1[0] + u0[1]*w1[1] + u0[2]*w1[2];
  double p1[3] = {w1[0]-d01*u0[0], w1[1]-d01*u0[1], w1[2]-d01*u0[2]};
  double n1 = sqrt(p1[0]*p1[0] + p1[1]*p1[1] + p1[2]*p1[2]);
  double u1[3];
  if (n1 > 1e-150) {
    double r1 = 1.0 / n1;
    u1[0] = p1[0]*r1; u1[1] = p1[1]*r1; u1[2] = p1[2]*r1;
  } else {
    double a0, a1, a2;
    if (fabs(u0[0]) < 0.7) { a0 = 1.0; a1 = 0.0; a2 = 0.0; }
    else                   { a0 = 0.0; a1 = 1.0; a2 = 0.0; }
    double c0 = u0[1]*a2 - u0[2]*a1;
    double c1 = u0[2]*a0 - u0[0]*a2;
    double c2 = u0[0]*a1 - u0[1]*a0;
    double nc = sqrt(c0*c0 + c1*c1 + c2*c2);
    double rc = 1.0 / nc;
    u1[0] = c0*rc; u1[1] = c1*rc; u1[2] = c2*rc;
  }

  double u2[3] = {u0[1]*u1[2] - u0[2]*u1[1],
                  u0[2]*u1[0] - u0[0]*u1[2],
                  u0[0]*u1[1] - u0[1]*u1[0]};
  double s2 = u2[0]*w2[0] + u2[1]*w2[1] + u2[2]*w2[2];
  if (s2 < 0.0) { u2[0] = -u2[0]; u2[1] = -u2[1]; u2[2] = -u2[2]; }

  #pragma unroll
  for (int i = 0; i < 3; ++i) {
    #pragma unroll
    for (int j = 0; j < 3; ++j) {
      Q[i][j] = u0[i]*v0[j] + u1[i]*v1[j] + u2[i]*v2[j];
    }
  }
}

// ---------------- fused GEMM2 + head: LDS-free K-loop; LDS only for h1 epilogue --------------
// BM=128, BN=256(=H1), K=512. 512 thr = 8 waves (2M x 4N), per-wave 64x64.
#define G2_K 512

__global__ __launch_bounds__(512, 2)
void gemm2_head_kernel(const _Float16* __restrict__ Ah,
                       const _Float16* __restrict__ Al,
                       const _Float16* __restrict__ Bh,
                       const _Float16* __restrict__ Bl,
                       const float* __restrict__ b1,
                       const float* __restrict__ W2,
                       const float* __restrict__ b2,
                       float* __restrict__ out) {
  __shared__ float H[128][257];  // h1 tile for the head (128.5 KB)

  const int tid = threadIdx.x;
  const int lane = tid & 63;
  const int w = tid >> 6;          // wave 0..7; 2M x 4N
  const int wr = w >> 2, wc = w & 3;

  const long bm = (long)blockIdx.x * 128;

  const int fr = lane & 15;
  const int kg = lane >> 4;

  unsigned oA[4], oB[4];
  #pragma unroll
  for (int m = 0; m < 4; ++m)
    oA[m] = (unsigned)((bm + (wr * 4 + m) * 16 + fr) * G2_K + kg * 8);
  #pragma unroll
  for (int n = 0; n < 4; ++n)
    oB[n] = (unsigned)(((wc * 4 + n) * 16 + fr) * G2_K + kg * 8);

  f32x4 acc_h[4][4] = {};
  f32x4 acc_c[4][4] = {};

  // ---- prologue: prefetch step-0 A pair + Bh
  half8 ahr[4], alr[4], bhr[4];
  #pragma unroll
  for (int m = 0; m < 4; ++m) {
    ahr[m] = *(const half8*)(Ah + oA[m]);
    alr[m] = *(const half8*)(Al + oA[m]);
  }
  #pragma unroll
  for (int n = 0; n < 4; ++n) bhr[n] = *(const half8*)(Bh + oB[n]);

  for (int kt = 0; kt < G2_K; kt += 32) {
    const bool has_next = (kt + 32 < G2_K);

    // issue Bl(t); take cur regs; issue next prefetch
    half8 bl[4];
    #pragma unroll
    for (int n = 0; n < 4; ++n) bl[n] = *(const half8*)(Bl + oB[n]);
    half8 ah[4], al[4], bh[4];
    #pragma unroll
    for (int m = 0; m < 4; ++m) { ah[m] = ahr[m]; al[m] = alr[m]; }
    #pragma unroll
    for (int n = 0; n < 4; ++n) bh[n] = bhr[n];
    if (has_next) {
      #pragma unroll
      for (int m = 0; m < 4; ++m) {
        oA[m] += 32;
        ahr[m] = *(const half8*)(Ah + oA[m]);
        alr[m] = *(const half8*)(Al + oA[m]);
      }
      #pragma unroll
      for (int n = 0; n < 4; ++n) {
        oB[n] += 32;
        bhr[n] = *(const half8*)(Bh + oB[n]);
      }
    }

    #pragma unroll
    for (int m = 0; m < 4; ++m)
      #pragma unroll
      for (int n = 0; n < 4; ++n)
        acc_h[m][n] = __builtin_amdgcn_mfma_f32_16x16x32_f16(ah[m], bh[n], acc_h[m][n], 0, 0, 0);
    #pragma unroll
    for (int m = 0; m < 4; ++m)
      #pragma unroll
      for (int n = 0; n < 4; ++n)
        acc_c[m][n] = __builtin_amdgcn_mfma_f32_16x16x32_f16(ah[m], bl[n], acc_c[m][n], 0, 0, 0);
    #pragma unroll
    for (int m = 0; m < 4; ++m)
      #pragma unroll
      for (int n = 0; n < 4; ++n)
        acc_c[m][n] = __builtin_amdgcn_mfma_f32_16x16x32_f16(al[m], bh[n], acc_c[m][n], 0, 0, 0);
  }

  // ---- epilogue A: bias+relu, dump h1 slice to LDS
  const float inv2048 = 1.0f / 2048.0f;
  #pragma unroll
  for (int m = 0; m < 4; ++m) {
    #pragma unroll
    for (int n = 0; n < 4; ++n) {
      int col = wc * 64 + n * 16 + (lane & 15);
      float bv = b1[col];
      int row0 = wr * 64 + m * 16 + (lane >> 4) * 4;
      #pragma unroll
      for (int j = 0; j < 4; ++j) {
        float v = acc_h[m][n][j] + acc_c[m][n][j] * inv2048 + bv;
        H[row0 + j][col] = fmaxf(v, 0.0f);
      }
    }
  }
  __syncthreads();

  // ---- epilogue B: per-sample head (128 rows, 1 thread each)
  if (tid < 128) {
    const float* hr = &H[tid][0];
    float r[9];
    #pragma unroll
    for (int j = 0; j < 9; ++j) r[j] = b2[j];
    #pragma unroll 4
    for (int k = 0; k < 256; k += 8) {
      #pragma unroll
      for (int kk = 0; kk < 4; ++kk) {
        float hvv = hr[k + kk];
        #pragma unroll
        for (int j = 0; j < 9; ++j) r[j] += hvv * W2[(k + kk) * 9 + j];
      }
      #pragma unroll
      for (int kk = 0; kk < 4; ++kk) {
        float hvv = hr[k + 4 + kk];
        #pragma unroll
        for (int j = 0; j < 9; ++j) r[j] += hvv * W2[(k + 4 + kk) * 9 + j];
      }
    }

    double R[3][3], Q[3][3];
    #pragma unroll
    for (int i = 0; i < 3; ++i) {
      #pragma unroll
      for (int j = 0; j < 3; ++j) {
        R[i][j] = (double)r[i * 3 + j] + ((i == j) ? 1e-3 : 0.0);
      }
    }
    polar3x3(R, Q);

    const size_t row = bm + tid;
    #pragma unroll
    for (int i = 0; i < 3; ++i) {
      #pragma unroll
      for (int j = 0; j < 3; ++j) {
        out[row * 9 + i * 3 + j] = (float)Q[i][j];
      }
    }
  }
}

// ---------------- launch ----------------
extern "C" void kernel_launch(void* const* d_in, const int* in_sizes, int n_in,
                              void* d_out, int out_size, void* d_ws, size_t ws_size,
                              hipStream_t stream) {
  const float* x  = (const float*)d_in[0];
  const float* W0 = (const float*)d_in[1];
  const float* b0 = (const float*)d_in[2];
  const float* W1 = (const float*)d_in[3];
  const float* b1 = (const float*)d_in[4];
  const float* W2 = (const float*)d_in[5];
  const float* b2 = (const float*)d_in[6];
  float* out = (float*)d_out;

  const int M = 131072, D = 1024, H0 = 512, H1 = 256;

  // Workspace: [h0h 128MB][h0l 128MB][W0hT][W0lT][W1hT][W1lT]  (~258.5 MB)
  char* ws = (char*)d_ws;
  _Float16* h0h = (_Float16*)ws;
  _Float16* h0l = (_Float16*)(ws + (size_t)M * H0 * 2);
  char* wp = ws + (size_t)M * H0 * 4;
  _Float16* W0hT = (_Float16*)wp;  wp += (size_t)D * H0 * 2;
  _Float16* W0lT = (_Float16*)wp;  wp += (size_t)D * H0 * 2;
  _Float16* W1hT = (_Float16*)wp;  wp += (size_t)H0 * H1 * 2;
  _Float16* W1lT = (_Float16*)wp;

  split_transpose_kernel<<<(D * H0 + 255) / 256, 256, 0, stream>>>(W0, W0hT, W0lT, D, H0);
  split_transpose_kernel<<<(H0 * H1 + 255) / 256, 256, 0, stream>>>(W1, W1hT, W1lT, H0, H1);

  // GEMM1: x(fp32, split in-reg) -> h0 split fp16 pair; grid = (M/128)*(H0/128) = 4096
  gemm1_direct_kernel<<<(M / 128) * (H0 / 128), 256, 0, stream>>>(
      x, W0hT, W0lT, b0, h0h, h0l, D, H0);

  // fused GEMM2 + head: h0 pair -> out; grid = M/128 = 1024
  gemm2_head_kernel<<<M / 128, 512, 0, stream>>>(
      h0h, h0l, W1hT, W1lT, b1, W2, b2, out);
}

// Round 12
// 1061.730 us; speedup vs baseline: 1.9253x; 1.9253x over previous
//
#include <hip/hip_runtime.h>
#include <hip/hip_bf16.h>
#include <math.h>

typedef _Float16 half8 __attribute__((ext_vector_type(8)));
typedef float f32x4 __attribute__((ext_vector_type(4)));

// async global->LDS, 16B per lane; LDS dest is wave-uniform base (HW adds lane*16)
__device__ __forceinline__ void glds16(const void* g, void* l) {
  __builtin_amdgcn_global_load_lds(
      (const __attribute__((address_space(1))) void*)g,
      (__attribute__((address_space(3))) void*)l, 16, 0, 0);
}

// ---------------- prep: split W (KxN fp32) into hi/lo fp16, transposed to NxK ----------------
__global__ void split_transpose_kernel(const float* __restrict__ W,
                                       _Float16* __restrict__ WhT,
                                       _Float16* __restrict__ WlT,
                                       int K, int N) {
  int idx = blockIdx.x * 256 + threadIdx.x;
  if (idx >= K * N) return;
  int k = idx / N, n = idx - k * N;
  float w = W[idx];
  _Float16 h = (_Float16)w;
  float r = w - (float)h;               // exact
  _Float16 l = (_Float16)(r * 2048.0f); // scaled residual stays fp16-normal
  WhT[(size_t)n * K + k] = h;
  WlT[(size_t)n * K + k] = l;
}

// ---------------- GEMM1: h0pair = relu(x @ W0 + b0), fp16x3 --------------------------------
// R8 structure with ONE change: B (W0-pair, 2MB, L2-resident) read DIRECT from global
// instead of LDS-staged. A (x fp32) stays LDS-staged with in-loop split (R8-proven).
// LDS halves to 32KB; B ds_reads -> global loads (same register count, no new prefetch regs).
__global__ __launch_bounds__(256, 2)
void gemm1_kernel(const float* __restrict__ A32,
                  const _Float16* __restrict__ Bh,
                  const _Float16* __restrict__ Bl,
                  const float* __restrict__ bias,
                  _Float16* __restrict__ Ch,
                  _Float16* __restrict__ Cl,
                  int K, int N) {
  // fragment-order LDS: slot = frag*64 + lane; lane l holds [row=l&15][k=(l>>4)*8 ..+8]
  __shared__ half8 AhS[2][512], AlS[2][512];  // 32 KB

  const int tid = threadIdx.x;
  const int lane = tid & 63;
  const int w = tid >> 6;          // wave 0..3, 2x2 wave grid
  const int wr = w >> 1, wc = w & 1;

  // 1-D grid, bijective XCD swizzle (gridDim.x % 8 == 0), N-tile fastest for L2 A-reuse
  const int cpx = gridDim.x >> 3;
  const int wg = (blockIdx.x & 7) * cpx + (blockIdx.x >> 3);
  const int ntiles = N >> 7;
  const int nT = wg % ntiles;
  const int mT = wg / ntiles;
  const long bm = (long)mT * 128;
  const long bn = (long)nT * 128;

  // A staging pointers (fp32 source; 2 slots/thread covering 128 rows x 32 k)
  const float* pA32[2];
  #pragma unroll
  for (int it = 0; it < 2; ++it) {
    const int s = tid + (it << 8);
    pA32[it] = A32 + (size_t)(bm + (s >> 6) * 16 + (s & 15)) * K + ((s >> 4) & 3) * 8;
  }

  // B direct per-lane element offsets (MFMA B-operand: row=lane&15, 8 k-contig at (lane>>4)*8)
  const int fr = lane & 15;
  const int kg = lane >> 4;
  unsigned oB[2];
  #pragma unroll
  for (int n = 0; n < 2; ++n)   // 2 base frags; +16*K and +32*K... use 4 separately below
    oB[n] = 0;
  unsigned oBf[4];
  #pragma unroll
  for (int n = 0; n < 4; ++n)
    oBf[n] = (unsigned)((bn + (wc * 4 + n) * 16 + fr) * K + kg * 8);

  f32x4 acc_h[4][4] = {};
  f32x4 acc_c[4][4] = {};

  auto convert_write = [&](int buf, f32x4 x0, f32x4 x1, int slot) {
    half8 hh, hl;
    #pragma unroll
    for (int e = 0; e < 4; ++e) {
      float xv = x0[e];
      _Float16 hv = (_Float16)xv;
      hh[e] = hv;
      hl[e] = (_Float16)((xv - (float)hv) * 2048.0f);
      float yv = x1[e];
      _Float16 hw = (_Float16)yv;
      hh[e + 4] = hw;
      hl[e + 4] = (_Float16)((yv - (float)hw) * 2048.0f);
    }
    AhS[buf][slot] = hh;
    AlS[buf][slot] = hl;
  };

  // ---- prologue: stage A tile 0 into buf 0
  #pragma unroll
  for (int it = 0; it < 2; ++it) {
    f32x4 x0 = *(const f32x4*)pA32[it];
    f32x4 x1 = *(const f32x4*)(pA32[it] + 4);
    convert_write(0, x0, x1, tid + (it << 8));
  }
  __syncthreads();

  for (int kt = 0; kt < K; kt += 32) {
    const int cur = (kt >> 5) & 1;
    const int nxt = cur ^ 1;
    const bool has_next = (kt + 32 < K);

    // ---- B direct loads for CURRENT step (L2-hot; latency hides under A ds_reads)
    half8 bh[4], bl[4];
    #pragma unroll
    for (int n = 0; n < 4; ++n) {
      bh[n] = *(const half8*)(Bh + oBf[n]);
      bl[n] = *(const half8*)(Bl + oBf[n]);
      oBf[n] += 32;
    }

    // ---- issue A fp32 loads for NEXT step (overlap MFMA; convert+write after MFMA)
    f32x4 a0_0, a0_1, a1_0, a1_1;
    if (has_next) {
      pA32[0] += 32; pA32[1] += 32;
      a0_0 = *(const f32x4*)pA32[0];
      a0_1 = *(const f32x4*)(pA32[0] + 4);
      a1_0 = *(const f32x4*)pA32[1];
      a1_1 = *(const f32x4*)(pA32[1] + 4);
    }

    // ---- compute(cur): 48 MFMA per wave (order identical to R8)
    #pragma unroll
    for (int m = 0; m < 4; ++m) {
      int mf = wr * 4 + m;
      half8 ah = AhS[cur][mf * 64 + lane];
      half8 al = AlS[cur][mf * 64 + lane];
      #pragma unroll
      for (int n = 0; n < 4; ++n) {
        acc_h[m][n] = __builtin_amdgcn_mfma_f32_16x16x32_f16(ah, bh[n], acc_h[m][n], 0, 0, 0);
        acc_c[m][n] = __builtin_amdgcn_mfma_f32_16x16x32_f16(ah, bl[n], acc_c[m][n], 0, 0, 0);
        acc_c[m][n] = __builtin_amdgcn_mfma_f32_16x16x32_f16(al, bh[n], acc_c[m][n], 0, 0, 0);
      }
    }

    // ---- finish A stage(next): convert + LDS write (after MFMA cluster)
    if (has_next) {
      convert_write(nxt, a0_0, a0_1, tid);
      convert_write(nxt, a1_0, a1_1, tid + 256);
    }
    __syncthreads();  // A dbuf hand-off (1 barrier per K-step, as R8)
  }

  // ---- epilogue: combine, bias, relu, split-store (R8-identical)
  const float inv2048 = 1.0f / 2048.0f;
  #pragma unroll
  for (int m = 0; m < 4; ++m) {
    #pragma unroll
    for (int n = 0; n < 4; ++n) {
      long col = bn + wc * 64 + n * 16 + (lane & 15);
      float bv = bias[col];
      long row0 = bm + wr * 64 + m * 16 + (lane >> 4) * 4;
      #pragma unroll
      for (int j = 0; j < 4; ++j) {
        float v = acc_h[m][n][j] + acc_c[m][n][j] * inv2048 + bv;
        v = fmaxf(v, 0.0f);
        size_t idx = (size_t)(row0 + j) * N + col;
        _Float16 hv = (_Float16)v;
        Ch[idx] = hv;
        Cl[idx] = (_Float16)((v - (float)hv) * 2048.0f);
      }
    }
  }
}

// ---------------- fp64 polar: Q = U Vh of 3x3 R via Jacobi eigen of R^T R + GS ----------------
__device__ __forceinline__ void polar3x3(const double R[3][3], double Q[3][3]) {
  double S[3][3], V[3][3];
  #pragma unroll
  for (int i = 0; i < 3; ++i) {
    #pragma unroll
    for (int j = 0; j < 3; ++j) {
      S[i][j] = R[0][i] * R[0][j] + R[1][i] * R[1][j] + R[2][i] * R[2][j];
      V[i][j] = (i == j) ? 1.0 : 0.0;
    }
  }

#define JROT(p, q, rr)                                                        \
  {                                                                           \
    double apq = S[p][q];                                                     \
    if (fabs(apq) > 1e-300) {                                                 \
      double tau = (S[q][q] - S[p][p]) / (2.0 * apq);                         \
      double t = copysign(1.0, tau) / (fabs(tau) + sqrt(1.0 + tau * tau));    \
      double c = 1.0 / sqrt(1.0 + t * t);                                     \
      double s = t * c;                                                       \
      S[p][p] -= t * apq;                                                     \
      S[q][q] += t * apq;                                                     \
      S[p][q] = 0.0; S[q][p] = 0.0;                                           \
      double srp = c * S[rr][p] - s * S[rr][q];                               \
      double srq = s * S[rr][p] + c * S[rr][q];                               \
      S[rr][p] = srp; S[p][rr] = srp; S[rr][q] = srq; S[q][rr] = srq;         \
      _Pragma("unroll")                                                       \
      for (int i = 0; i < 3; ++i) {                                           \
        double vip = V[i][p], viq = V[i][q];                                  \
        V[i][p] = c * vip - s * viq;                                          \
        V[i][q] = s * vip + c * viq;                                          \
      }                                                                       \
    }                                                                         \
  }

  #pragma unroll 1
  for (int sweep = 0; sweep < 6; ++sweep) {
    JROT(0, 1, 2)
    JROT(0, 2, 1)
    JROT(1, 2, 0)
  }
#undef JROT

  double l0 = S[0][0], l1 = S[1][1], l2 = S[2][2];
  double v0[3] = {V[0][0], V[1][0], V[2][0]};
  double v1[3] = {V[0][1], V[1][1], V[2][1]};
  double v2[3] = {V[0][2], V[1][2], V[2][2]};

#define CSWAPV(la, lb, va, vb)                                                \
  if (la < lb) {                                                              \
    double tt = la; la = lb; lb = tt;                                         \
    _Pragma("unroll")                                                         \
    for (int i = 0; i < 3; ++i) { double tv = va[i]; va[i] = vb[i]; vb[i] = tv; } \
  }
  CSWAPV(l0, l1, v0, v1)
  CSWAPV(l0, l2, v0, v2)
  CSWAPV(l1, l2, v1, v2)
#undef CSWAPV

  double w0[3], w1[3], w2[3];
  #pragma unroll
  for (int i = 0; i < 3; ++i) {
    w0[i] = R[i][0] * v0[0] + R[i][1] * v0[1] + R[i][2] * v0[2];
    w1[i] = R[i][0] * v1[0] + R[i][1] * v1[1] + R[i][2] * v1[2];
    w2[i] = R[i][0] * v2[0] + R[i][1] * v2[1] + R[i][2] * v2[2];
  }

  double n0 = sqrt(w0[0]*w0[0] + w0[1]*w0[1] + w0[2]*w0[2]);
  double u0[3];
  if (n0 > 1e-150) {
    double r0 = 1.0 / n0;
    u0[0] = w0[0]*r0; u0[1] = w0[1]*r0; u0[2] = w0[2]*r0;
  } else { u0[0] = 1.0; u0[1] = 0.0; u0[2] = 0.0; }

  double d01 = u0[0]*w1[0] + u0[1]*w1[1] + u0[2]*w1[2];
  double p1[3] = {w1[0]-d01*u0[0], w1[1]-d01*u0[1], w1[2]-d01*u0[2]};
  double n1 = sqrt(p1[0]*p1[0] + p1[1]*p1[1] + p1[2]*p1[2]);
  double u1[3];
  if (n1 > 1e-150) {
    double r1 = 1.0 / n1;
    u1[0] = p1[0]*r1; u1[1] = p1[1]*r1; u1[2] = p1[2]*r1;
  } else {
    double a0, a1, a2;
    if (fabs(u0[0]) < 0.7) { a0 = 1.0; a1 = 0.0; a2 = 0.0; }
    else                   { a0 = 0.0; a1 = 1.0; a2 = 0.0; }
    double c0 = u0[1]*a2 - u0[2]*a1;
    double c1 = u0[2]*a0 - u0[0]*a2;
    double c2 = u0[0]*a1 - u0[1]*a0;
    double nc = sqrt(c0*c0 + c1*c1 + c2*c2);
    double rc = 1.0 / nc;
    u1[0] = c0*rc; u1[1] = c1*rc; u1[2] = c2*rc;
  }

  double u2[3] = {u0[1]*u1[2] - u0[2]*u1[1],
                  u0[2]*u1[0] - u0[0]*u1[2],
                  u0[0]*u1[1] - u0[1]*u1[0]};
  double s2 = u2[0]*w2[0] + u2[1]*w2[1] + u2[2]*w2[2];
  if (s2 < 0.0) { u2[0] = -u2[0]; u2[1] = -u2[1]; u2[2] = -u2[2]; }

  #pragma unroll
  for (int i = 0; i < 3; ++i) {
    #pragma unroll
    for (int j = 0; j < 3; ++j) {
      Q[i][j] = u0[i]*v0[j] + u1[i]*v1[j] + u2[i]*v2[j];
    }
  }
}

// ---------------- fused GEMM2 + head: A LDS-staged (glds16), B (W1, L2-resident) direct ------
// BM=128, BN=256(=H1), K=512. 512 thr = 8 waves (2M x 4N), per-wave 64x64.
#define G2_K 512
#define G2_T (G2_K / 32)
#define A_SLOTS 1024  // Ah 512 | Al 512  (x16B = 16KB per buffer)

__global__ __launch_bounds__(512, 2)
void gemm2_head_kernel(const _Float16* __restrict__ Ah,
                       const _Float16* __restrict__ Al,
                       const _Float16* __restrict__ Bh,
                       const _Float16* __restrict__ Bl,
                       const float* __restrict__ b1,
                       const float* __restrict__ W2,
                       const float* __restrict__ b2,
                       float* __restrict__ out) {
  // union LDS: A staging (2 x 16KB) during K-loop; h1[128][257] f32 (131584 B) in epilogue
  __shared__ __align__(16) char SM[131584];
  half8* S8 = (half8*)SM;

  const int tid = threadIdx.x;
  const int lane = tid & 63;
  const int w = tid >> 6;          // wave 0..7; 2M x 4N
  const int wr = w >> 2, wc = w & 3;
  const int wbase = w << 6;

  const long bm = (long)blockIdx.x * 128;

  // A staging pointer (h0 pair via glds16; 1 slot/thread covers 128 rows x 32 k)
  const _Float16 *pAh, *pAl;
  {
    const int s0 = tid;
    const size_t goA = (size_t)(bm + (s0 >> 6) * 16 + (s0 & 15)) * G2_K + ((s0 >> 4) & 3) * 8;
    pAh = Ah + goA;  pAl = Al + goA;
  }

  // B direct per-lane element offsets
  const int fr = lane & 15;
  const int kg = lane >> 4;
  unsigned oB[4];
  #pragma unroll
  for (int n = 0; n < 4; ++n)
    oB[n] = (unsigned)(((wc * 4 + n) * 16 + fr) * G2_K + kg * 8);

  f32x4 acc_h[4][4] = {};
  f32x4 acc_c[4][4] = {};

  auto stage = [&](int b) {  // 2 glds per thread per tile (A only)
    half8* base = S8 + b * A_SLOTS;
    glds16(pAh, base + wbase);
    glds16(pAl, base + 512 + wbase);
    pAh += 32; pAl += 32;
  };

  stage(0);
  __syncthreads();

  for (int t = 0; t < G2_T; ++t) {
    const int cur = t & 1;
    const int nxt = cur ^ 1;
    if (t + 1 < G2_T) stage(nxt);  // issue A(next) before compute

    // B direct loads (L2-hot W1 pair)
    half8 bh[4], bl[4];
    #pragma unroll
    for (int n = 0; n < 4; ++n) {
      bh[n] = *(const half8*)(Bh + oB[n]);
      bl[n] = *(const half8*)(Bl + oB[n]);
      oB[n] += 32;
    }

    half8* base = S8 + cur * A_SLOTS;
    #pragma unroll
    for (int m = 0; m < 4; ++m) {
      int mf = wr * 4 + m;
      half8 ah = base[mf * 64 + lane];
      half8 al = base[512 + mf * 64 + lane];
      #pragma unroll
      for (int n = 0; n < 4; ++n) {
        acc_h[m][n] = __builtin_amdgcn_mfma_f32_16x16x32_f16(ah, bh[n], acc_h[m][n], 0, 0, 0);
        acc_c[m][n] = __builtin_amdgcn_mfma_f32_16x16x32_f16(ah, bl[n], acc_c[m][n], 0, 0, 0);
        acc_c[m][n] = __builtin_amdgcn_mfma_f32_16x16x32_f16(al, bh[n], acc_c[m][n], 0, 0, 0);
      }
    }
    __syncthreads();
  }

  // ---- epilogue A: bias+relu, dump h1 slice to LDS (staging buffers dead)
  float* H = (float*)SM;  // h1[128][257]
  const float inv2048 = 1.0f / 2048.0f;
  #pragma unroll
  for (int m = 0; m < 4; ++m) {
    #pragma unroll
    for (int n = 0; n < 4; ++n) {
      int col = wc * 64 + n * 16 + (lane & 15);
      float bv = b1[col];
      int row0 = wr * 64 + m * 16 + (lane >> 4) * 4;
      #pragma unroll
      for (int j = 0; j < 4; ++j) {
        float v = acc_h[m][n][j] + acc_c[m][n][j] * inv2048 + bv;
        H[(row0 + j) * 257 + col] = fmaxf(v, 0.0f);
      }
    }
  }
  __syncthreads();

  // ---- epilogue B: per-sample head (128 rows, 1 thread each)
  if (tid < 128) {
    const float* hr = H + tid * 257;
    float r[9];
    #pragma unroll
    for (int j = 0; j < 9; ++j) r[j] = b2[j];
    #pragma unroll 4
    for (int k = 0; k < 256; k += 8) {
      #pragma unroll
      for (int kk = 0; kk < 4; ++kk) {
        float hvv = hr[k + kk];
        #pragma unroll
        for (int j = 0; j < 9; ++j) r[j] += hvv * W2[(k + kk) * 9 + j];
      }
      #pragma unroll
      for (int kk = 0; kk < 4; ++kk) {
        float hvv = hr[k + 4 + kk];
        #pragma unroll
        for (int j = 0; j < 9; ++j) r[j] += hvv * W2[(k + 4 + kk) * 9 + j];
      }
    }

    double R[3][3], Q[3][3];
    #pragma unroll
    for (int i = 0; i < 3; ++i) {
      #pragma unroll
      for (int j = 0; j < 3; ++j) {
        R[i][j] = (double)r[i * 3 + j] + ((i == j) ? 1e-3 : 0.0);
      }
    }
    polar3x3(R, Q);

    const size_t row = bm + tid;
    #pragma unroll
    for (int i = 0; i < 3; ++i) {
      #pragma unroll
      for (int j = 0; j < 3; ++j) {
        out[row * 9 + i * 3 + j] = (float)Q[i][j];
      }
    }
  }
}

// ---------------- launch ----------------
extern "C" void kernel_launch(void* const* d_in, const int* in_sizes, int n_in,
                              void* d_out, int out_size, void* d_ws, size_t ws_size,
                              hipStream_t stream) {
  const float* x  = (const float*)d_in[0];
  const float* W0 = (const float*)d_in[1];
  const float* b0 = (const float*)d_in[2];
  const float* W1 = (const float*)d_in[3];
  const float* b1 = (const float*)d_in[4];
  const float* W2 = (const float*)d_in[5];
  const float* b2 = (const float*)d_in[6];
  float* out = (float*)d_out;

  const int M = 131072, D = 1024, H0 = 512, H1 = 256;

  // Workspace: [h0h 128MB][h0l 128MB][W0hT][W0lT][W1hT][W1lT]  (~258.5 MB)
  char* ws = (char*)d_ws;
  _Float16* h0h = (_Float16*)ws;
  _Float16* h0l = (_Float16*)(ws + (size_t)M * H0 * 2);
  char* wp = ws + (size_t)M * H0 * 4;
  _Float16* W0hT = (_Float16*)wp;  wp += (size_t)D * H0 * 2;
  _Float16* W0lT = (_Float16*)wp;  wp += (size_t)D * H0 * 2;
  _Float16* W1hT = (_Float16*)wp;  wp += (size_t)H0 * H1 * 2;
  _Float16* W1lT = (_Float16*)wp;

  split_transpose_kernel<<<(D * H0 + 255) / 256, 256, 0, stream>>>(W0, W0hT, W0lT, D, H0);
  split_transpose_kernel<<<(H0 * H1 + 255) / 256, 256, 0, stream>>>(W1, W1hT, W1lT, H0, H1);

  // GEMM1: x(fp32, split in-loop) -> h0 split fp16 pair; grid = (M/128)*(H0/128) = 4096
  gemm1_kernel<<<(M / 128) * (H0 / 128), 256, 0, stream>>>(
      x, W0hT, W0lT, b0, h0h, h0l, D, H0);

  // fused GEMM2 + head: h0 pair -> out; grid = M/128 = 1024
  gemm2_head_kernel<<<M / 128, 512, 0, stream>>>(
      h0h, h0l, W1hT, W1lT, b1, W2, b2, out);
}

// Round 13
// 789.945 us; speedup vs baseline: 2.5877x; 1.3441x over previous
//
#include <hip/hip_runtime.h>
#include <hip/hip_bf16.h>
#include <math.h>

typedef _Float16 half8 __attribute__((ext_vector_type(8)));
typedef float f32x4 __attribute__((ext_vector_type(4)));

// async global->LDS, 16B per lane; LDS dest is wave-uniform base (HW adds lane*16)
__device__ __forceinline__ void glds16(const void* g, void* l) {
  __builtin_amdgcn_global_load_lds(
      (const __attribute__((address_space(1))) void*)g,
      (__attribute__((address_space(3))) void*)l, 16, 0, 0);
}

// ---------------- prep: split W (KxN fp32) into hi/lo fp16, transposed to NxK ----------------
__global__ void split_transpose_kernel(const float* __restrict__ W,
                                       _Float16* __restrict__ WhT,
                                       _Float16* __restrict__ WlT,
                                       int K, int N) {
  int idx = blockIdx.x * 256 + threadIdx.x;
  if (idx >= K * N) return;
  int k = idx / N, n = idx - k * N;
  float w = W[idx];
  _Float16 h = (_Float16)w;
  float r = w - (float)h;               // exact
  _Float16 l = (_Float16)(r * 2048.0f); // scaled residual stays fp16-normal
  WhT[(size_t)n * K + k] = h;
  WlT[(size_t)n * K + k] = l;
}

// ---------------- GEMM1: C = relu(A @ B + bias), fp16x3, R4/R8-proven 2-phase dbuf -----------
// A_FP32: A fp32, split in-register while staging. OUT_SPLIT: store C as fp16 hi/lo pair.
template <bool A_FP32, bool OUT_SPLIT>
__global__ __launch_bounds__(256, 2)
void gemm_split_kernel(const float* __restrict__ A32,
                       const _Float16* __restrict__ Ah,
                       const _Float16* __restrict__ Al,
                       const _Float16* __restrict__ Bh,
                       const _Float16* __restrict__ Bl,
                       const float* __restrict__ bias,
                       float* __restrict__ C32,
                       _Float16* __restrict__ Ch,
                       _Float16* __restrict__ Cl,
                       int K, int N) {
  // fragment-order LDS: slot = frag*64 + lane; lane l holds [row=l&15][k=(l>>4)*8 ..+8]
  __shared__ half8 AhS[2][512], AlS[2][512], BhS[2][512], BlS[2][512];  // 64 KB

  const int tid = threadIdx.x;
  const int lane = tid & 63;
  const int w = tid >> 6;          // wave 0..3, 2x2 wave grid
  const int wr = w >> 1, wc = w & 1;
  const int wbase = w << 6;        // wave-uniform slot base

  // 1-D grid, bijective XCD swizzle (gridDim.x % 8 == 0), N-tile fastest for L2 A-reuse
  const int cpx = gridDim.x >> 3;
  const int wg = (blockIdx.x & 7) * cpx + (blockIdx.x >> 3);
  const int ntiles = N >> 7;
  const int nT = wg % ntiles;
  const int mT = wg / ntiles;
  const long bm = (long)mT * 128;
  const long bn = (long)nT * 128;

  // per-thread global source pointers (advance by 32 elements of K per step)
  const _Float16* pBh[2];
  const _Float16* pBl[2];
  const float*    pA32[2];
  const _Float16* pAh[2];
  const _Float16* pAl[2];
  #pragma unroll
  for (int it = 0; it < 2; ++it) {
    const int slot = wbase + (it << 8) + lane;
    const int fr = slot & 15, kg = (slot >> 4) & 3, frag = slot >> 6;
    const size_t goB = (size_t)(bn + frag * 16 + fr) * K + kg * 8;
    const size_t goA = (size_t)(bm + frag * 16 + fr) * K + kg * 8;
    pBh[it] = Bh + goB;
    pBl[it] = Bl + goB;
    if constexpr (A_FP32) {
      pA32[it] = A32 + goA;
    } else {
      pAh[it] = Ah + goA;
      pAl[it] = Al + goA;
    }
  }

  f32x4 acc_h[4][4] = {};
  f32x4 acc_c[4][4] = {};

  // ---- prologue: stage tile 0 into buf 0
  #pragma unroll
  for (int it = 0; it < 2; ++it) {
    const int sb = wbase + (it << 8);
    glds16(pBh[it], &BhS[0][sb]);
    glds16(pBl[it], &BlS[0][sb]);
    if constexpr (A_FP32) {
      f32x4 x0 = *(const f32x4*)pA32[it];
      f32x4 x1 = *(const f32x4*)(pA32[it] + 4);
      half8 hh, hl;
      #pragma unroll
      for (int e = 0; e < 4; ++e) {
        float xv = x0[e];
        _Float16 hv = (_Float16)xv;
        hh[e] = hv;
        hl[e] = (_Float16)((xv - (float)hv) * 2048.0f);
        float yv = x1[e];
        _Float16 hw = (_Float16)yv;
        hh[e + 4] = hw;
        hl[e + 4] = (_Float16)((yv - (float)hw) * 2048.0f);
      }
      AhS[0][sb + lane] = hh;
      AlS[0][sb + lane] = hl;
    } else {
      glds16(pAh[it], &AhS[0][sb]);
      glds16(pAl[it], &AlS[0][sb]);
    }
  }
  __syncthreads();

  for (int kt = 0; kt < K; kt += 32) {
    const int cur = (kt >> 5) & 1;
    const int nxt = cur ^ 1;
    const bool has_next = (kt + 32 < K);

    // ---- issue stage(next) BEFORE compute(cur): loads overlap MFMA below
    f32x4 a0_0, a0_1, a1_0, a1_1;  // staged A fp32 (write-late after MFMA)
    if (has_next) {
      #pragma unroll
      for (int it = 0; it < 2; ++it) {
        const int sb = wbase + (it << 8);
        pBh[it] += 32; pBl[it] += 32;
        glds16(pBh[it], &BhS[nxt][sb]);
        glds16(pBl[it], &BlS[nxt][sb]);
        if constexpr (!A_FP32) {
          pAh[it] += 32; pAl[it] += 32;
          glds16(pAh[it], &AhS[nxt][sb]);
          glds16(pAl[it], &AlS[nxt][sb]);
        }
      }
      if constexpr (A_FP32) {
        pA32[0] += 32; pA32[1] += 32;
        a0_0 = *(const f32x4*)pA32[0];
        a0_1 = *(const f32x4*)(pA32[0] + 4);
        a1_0 = *(const f32x4*)pA32[1];
        a1_1 = *(const f32x4*)(pA32[1] + 4);
      }
    }

    // ---- compute(cur): 48 MFMA per wave
    half8 bh[4], bl[4];
    #pragma unroll
    for (int n = 0; n < 4; ++n) {
      int nf = wc * 4 + n;
      bh[n] = BhS[cur][nf * 64 + lane];
      bl[n] = BlS[cur][nf * 64 + lane];
    }
    #pragma unroll
    for (int m = 0; m < 4; ++m) {
      int mf = wr * 4 + m;
      half8 ah = AhS[cur][mf * 64 + lane];
      half8 al = AlS[cur][mf * 64 + lane];
      #pragma unroll
      for (int n = 0; n < 4; ++n) {
        acc_h[m][n] = __builtin_amdgcn_mfma_f32_16x16x32_f16(ah, bh[n], acc_h[m][n], 0, 0, 0);
        acc_c[m][n] = __builtin_amdgcn_mfma_f32_16x16x32_f16(ah, bl[n], acc_c[m][n], 0, 0, 0);
        acc_c[m][n] = __builtin_amdgcn_mfma_f32_16x16x32_f16(al, bh[n], acc_c[m][n], 0, 0, 0);
      }
    }

    // ---- finish stage(next) for fp32-A: convert + LDS write (after MFMA cluster)
    if (has_next) {
      if constexpr (A_FP32) {
        #pragma unroll
        for (int it = 0; it < 2; ++it) {
          f32x4 x0 = it ? a1_0 : a0_0;
          f32x4 x1 = it ? a1_1 : a0_1;
          half8 hh, hl;
          #pragma unroll
          for (int e = 0; e < 4; ++e) {
            float xv = x0[e];
            _Float16 hv = (_Float16)xv;
            hh[e] = hv;
            hl[e] = (_Float16)((xv - (float)hv) * 2048.0f);
            float yv = x1[e];
            _Float16 hw = (_Float16)yv;
            hh[e + 4] = hw;
            hl[e + 4] = (_Float16)((yv - (float)hw) * 2048.0f);
          }
          const int sb = wbase + (it << 8);
          AhS[nxt][sb + lane] = hh;
          AlS[nxt][sb + lane] = hl;
        }
      }
    }
    __syncthreads();  // drains glds (vmcnt) + ds_writes (lgkm); next tile ready
  }

  // ---- epilogue: combine scales, bias, relu, store
  const float inv2048 = 1.0f / 2048.0f;
  #pragma unroll
  for (int m = 0; m < 4; ++m) {
    #pragma unroll
    for (int n = 0; n < 4; ++n) {
      long col = bn + wc * 64 + n * 16 + (lane & 15);
      float bv = bias[col];
      long row0 = bm + wr * 64 + m * 16 + (lane >> 4) * 4;
      #pragma unroll
      for (int j = 0; j < 4; ++j) {
        float v = acc_h[m][n][j] + acc_c[m][n][j] * inv2048 + bv;
        v = fmaxf(v, 0.0f);
        size_t idx = (size_t)(row0 + j) * N + col;
        if constexpr (OUT_SPLIT) {
          _Float16 hv = (_Float16)v;
          Ch[idx] = hv;
          Cl[idx] = (_Float16)((v - (float)hv) * 2048.0f);
        } else {
          C32[idx] = v;
        }
      }
    }
  }
}

// ---------------- fp64 polar: Q = U Vh of 3x3 R via Jacobi eigen of R^T R + GS ----------------
__device__ __forceinline__ void polar3x3(const double R[3][3], double Q[3][3]) {
  double S[3][3], V[3][3];
  #pragma unroll
  for (int i = 0; i < 3; ++i) {
    #pragma unroll
    for (int j = 0; j < 3; ++j) {
      S[i][j] = R[0][i] * R[0][j] + R[1][i] * R[1][j] + R[2][i] * R[2][j];
      V[i][j] = (i == j) ? 1.0 : 0.0;
    }
  }

#define JROT(p, q, rr)                                                        \
  {                                                                           \
    double apq = S[p][q];                                                     \
    if (fabs(apq) > 1e-300) {                                                 \
      double tau = (S[q][q] - S[p][p]) / (2.0 * apq);                         \
      double t = copysign(1.0, tau) / (fabs(tau) + sqrt(1.0 + tau * tau));    \
      double c = 1.0 / sqrt(1.0 + t * t);                                     \
      double s = t * c;                                                       \
      S[p][p] -= t * apq;                                                     \
      S[q][q] += t * apq;                                                     \
      S[p][q] = 0.0; S[q][p] = 0.0;                                           \
      double srp = c * S[rr][p] - s * S[rr][q];                               \
      double srq = s * S[rr][p] + c * S[rr][q];                               \
      S[rr][p] = srp; S[p][rr] = srp; S[rr][q] = srq; S[q][rr] = srq;         \
      _Pragma("unroll")                                                       \
      for (int i = 0; i < 3; ++i) {                                           \
        double vip = V[i][p], viq = V[i][q];                                  \
        V[i][p] = c * vip - s * viq;                                          \
        V[i][q] = s * vip + c * viq;                                          \
      }                                                                       \
    }                                                                         \
  }

  #pragma unroll 1
  for (int sweep = 0; sweep < 6; ++sweep) {
    JROT(0, 1, 2)
    JROT(0, 2, 1)
    JROT(1, 2, 0)
  }
#undef JROT

  double l0 = S[0][0], l1 = S[1][1], l2 = S[2][2];
  double v0[3] = {V[0][0], V[1][0], V[2][0]};
  double v1[3] = {V[0][1], V[1][1], V[2][1]};
  double v2[3] = {V[0][2], V[1][2], V[2][2]};

#define CSWAPV(la, lb, va, vb)                                                \
  if (la < lb) {                                                              \
    double tt = la; la = lb; lb = tt;                                         \
    _Pragma("unroll")                                                         \
    for (int i = 0; i < 3; ++i) { double tv = va[i]; va[i] = vb[i]; vb[i] = tv; } \
  }
  CSWAPV(l0, l1, v0, v1)
  CSWAPV(l0, l2, v0, v2)
  CSWAPV(l1, l2, v1, v2)
#undef CSWAPV

  double w0[3], w1[3], w2[3];
  #pragma unroll
  for (int i = 0; i < 3; ++i) {
    w0[i] = R[i][0] * v0[0] + R[i][1] * v0[1] + R[i][2] * v0[2];
    w1[i] = R[i][0] * v1[0] + R[i][1] * v1[1] + R[i][2] * v1[2];
    w2[i] = R[i][0] * v2[0] + R[i][1] * v2[1] + R[i][2] * v2[2];
  }

  double n0 = sqrt(w0[0]*w0[0] + w0[1]*w0[1] + w0[2]*w0[2]);
  double u0[3];
  if (n0 > 1e-150) {
    double r0 = 1.0 / n0;
    u0[0] = w0[0]*r0; u0[1] = w0[1]*r0; u0[2] = w0[2]*r0;
  } else { u0[0] = 1.0; u0[1] = 0.0; u0[2] = 0.0; }

  double d01 = u0[0]*w1[0] + u0[1]*w1[1] + u0[2]*w1[2];
  double p1[3] = {w1[0]-d01*u0[0], w1[1]-d01*u0[1], w1[2]-d01*u0[2]};
  double n1 = sqrt(p1[0]*p1[0] + p1[1]*p1[1] + p1[2]*p1[2]);
  double u1[3];
  if (n1 > 1e-150) {
    double r1 = 1.0 / n1;
    u1[0] = p1[0]*r1; u1[1] = p1[1]*r1; u1[2] = p1[2]*r1;
  } else {
    double a0, a1, a2;
    if (fabs(u0[0]) < 0.7) { a0 = 1.0; a1 = 0.0; a2 = 0.0; }
    else                   { a0 = 0.0; a1 = 1.0; a2 = 0.0; }
    double c0 = u0[1]*a2 - u0[2]*a1;
    double c1 = u0[2]*a0 - u0[0]*a2;
    double c2 = u0[0]*a1 - u0[1]*a0;
    double nc = sqrt(c0*c0 + c1*c1 + c2*c2);
    double rc = 1.0 / nc;
    u1[0] = c0*rc; u1[1] = c1*rc; u1[2] = c2*rc;
  }

  double u2[3] = {u0[1]*u1[2] - u0[2]*u1[1],
                  u0[2]*u1[0] - u0[0]*u1[2],
                  u0[0]*u1[1] - u0[1]*u1[0]};
  double s2 = u2[0]*w2[0] + u2[1]*w2[1] + u2[2]*w2[2];
  if (s2 < 0.0) { u2[0] = -u2[0]; u2[1] = -u2[1]; u2[2] = -u2[2]; }

  #pragma unroll
  for (int i = 0; i < 3; ++i) {
    #pragma unroll
    for (int j = 0; j < 3; ++j) {
      Q[i][j] = u0[i]*v0[j] + u1[i]*v1[j] + u2[i]*v2[j];
    }
  }
}

// ---------------- fused GEMM2 + head: h1 = relu(h0 @ W1 + b1) stays in LDS; ------------------
// then R = h1 @ W2 + b2, +eps*I, fp64 polar, write out. BM=128, BN=256(=H1 full), BK=32.
// 512 threads = 8 waves (2M x 4N), per-wave 64x64.
#define G2_K 512
#define G2_T (G2_K / 32)
#define SLOTS_PER_BUF 3072  // Ah 512 | Al 512 | Bh 1024 | Bl 1024  (x16B = 48KB)

__global__ __launch_bounds__(512, 2)
void gemm2_head_kernel(const _Float16* __restrict__ Ah,
                       const _Float16* __restrict__ Al,
                       const _Float16* __restrict__ Bh,
                       const _Float16* __restrict__ Bl,
                       const float* __restrict__ b1,
                       const float* __restrict__ W2,
                       const float* __restrict__ b2,
                       float* __restrict__ out) {
  // union LDS: staging (2 x 48KB) during K-loop; h1[128][257] f32 (131584 B) in epilogue
  __shared__ __align__(16) char SM[131584];
  half8* S8 = (half8*)SM;

  const int tid = threadIdx.x;
  const int lane = tid & 63;
  const int w = tid >> 6;          // wave 0..7; 2M x 4N
  const int wr = w >> 2, wc = w & 3;
  const int wbase = w << 6;

  const long bm = (long)blockIdx.x * 128;

  const _Float16 *pAh, *pAl, *pBh0, *pBh1, *pBl0, *pBl1;
  {
    const int s0 = tid, s1 = tid + 512;
    const size_t goA  = (size_t)(bm + (s0 >> 6) * 16 + (s0 & 15)) * G2_K + ((s0 >> 4) & 3) * 8;
    const size_t goB0 = (size_t)((s0 >> 6) * 16 + (s0 & 15)) * G2_K + ((s0 >> 4) & 3) * 8;
    const size_t goB1 = (size_t)((s1 >> 6) * 16 + (s1 & 15)) * G2_K + ((s1 >> 4) & 3) * 8;
    pAh = Ah + goA;  pAl = Al + goA;
    pBh0 = Bh + goB0; pBh1 = Bh + goB1;
    pBl0 = Bl + goB0; pBl1 = Bl + goB1;
  }

  f32x4 acc_h[4][4] = {};
  f32x4 acc_c[4][4] = {};

  auto stage = [&](int b) {  // 6 glds per thread per tile
    half8* base = S8 + b * SLOTS_PER_BUF;
    glds16(pAh,  base + wbase);
    glds16(pAl,  base + 512 + wbase);
    glds16(pBh0, base + 1024 + wbase);
    glds16(pBh1, base + 1024 + 512 + wbase);
    glds16(pBl0, base + 2048 + wbase);
    glds16(pBl1, base + 2048 + 512 + wbase);
    pAh += 32; pAl += 32; pBh0 += 32; pBh1 += 32; pBl0 += 32; pBl1 += 32;
  };

  stage(0);
  __syncthreads();

  for (int t = 0; t < G2_T; ++t) {
    const int cur = t & 1;
    const int nxt = cur ^ 1;
    if (t + 1 < G2_T) stage(nxt);  // issue before compute: loads overlap MFMA

    half8* base = S8 + cur * SLOTS_PER_BUF;
    half8 bh[4], bl[4];
    #pragma unroll
    for (int n = 0; n < 4; ++n) {
      int nf = wc * 4 + n;
      bh[n] = base[1024 + nf * 64 + lane];
      bl[n] = base[2048 + nf * 64 + lane];
    }
    #pragma unroll
    for (int m = 0; m < 4; ++m) {
      int mf = wr * 4 + m;
      half8 ah = base[mf * 64 + lane];
      half8 al = base[512 + mf * 64 + lane];
      #pragma unroll
      for (int n = 0; n < 4; ++n) {
        acc_h[m][n] = __builtin_amdgcn_mfma_f32_16x16x32_f16(ah, bh[n], acc_h[m][n], 0, 0, 0);
        acc_c[m][n] = __builtin_amdgcn_mfma_f32_16x16x32_f16(ah, bl[n], acc_c[m][n], 0, 0, 0);
        acc_c[m][n] = __builtin_amdgcn_mfma_f32_16x16x32_f16(al, bh[n], acc_c[m][n], 0, 0, 0);
      }
    }
    __syncthreads();
  }

  // ---- epilogue A: bias+relu, dump h1 slice to LDS (staging buffers dead)
  float* H = (float*)SM;  // h1[128][257]
  const float inv2048 = 1.0f / 2048.0f;
  #pragma unroll
  for (int m = 0; m < 4; ++m) {
    #pragma unroll
    for (int n = 0; n < 4; ++n) {
      int col = wc * 64 + n * 16 + (lane & 15);
      float bv = b1[col];
      int row0 = wr * 64 + m * 16 + (lane >> 4) * 4;
      #pragma unroll
      for (int j = 0; j < 4; ++j) {
        float v = acc_h[m][n][j] + acc_c[m][n][j] * inv2048 + bv;
        H[(row0 + j) * 257 + col] = fmaxf(v, 0.0f);
      }
    }
  }
  __syncthreads();

  // ---- epilogue B: per-sample head (128 rows, 1 thread each)
  if (tid < 128) {
    const float* hr = H + tid * 257;
    float r[9];
    #pragma unroll
    for (int j = 0; j < 9; ++j) r[j] = b2[j];
    #pragma unroll 4
    for (int k = 0; k < 256; k += 8) {
      #pragma unroll
      for (int kk = 0; kk < 4; ++kk) {
        float hvv = hr[k + kk];
        #pragma unroll
        for (int j = 0; j < 9; ++j) r[j] += hvv * W2[(k + kk) * 9 + j];
      }
      #pragma unroll
      for (int kk = 0; kk < 4; ++kk) {
        float hvv = hr[k + 4 + kk];
        #pragma unroll
        for (int j = 0; j < 9; ++j) r[j] += hvv * W2[(k + 4 + kk) * 9 + j];
      }
    }

    double R[3][3], Q[3][3];
    #pragma unroll
    for (int i = 0; i < 3; ++i) {
      #pragma unroll
      for (int j = 0; j < 3; ++j) {
        R[i][j] = (double)r[i * 3 + j] + ((i == j) ? 1e-3 : 0.0);
      }
    }
    polar3x3(R, Q);

    const size_t row = bm + tid;
    #pragma unroll
    for (int i = 0; i < 3; ++i) {
      #pragma unroll
      for (int j = 0; j < 3; ++j) {
        out[row * 9 + i * 3 + j] = (float)Q[i][j];
      }
    }
  }
}

// ---------------- launch ----------------
extern "C" void kernel_launch(void* const* d_in, const int* in_sizes, int n_in,
                              void* d_out, int out_size, void* d_ws, size_t ws_size,
                              hipStream_t stream) {
  const float* x  = (const float*)d_in[0];
  const float* W0 = (const float*)d_in[1];
  const float* b0 = (const float*)d_in[2];
  const float* W1 = (const float*)d_in[3];
  const float* b1 = (const float*)d_in[4];
  const float* W2 = (const float*)d_in[5];
  const float* b2 = (const float*)d_in[6];
  float* out = (float*)d_out;

  const int M = 131072, D = 1024, H0 = 512, H1 = 256;

  // Workspace: [h0h 128MB][h0l 128MB][W0hT][W0lT][W1hT][W1lT]  (~258.5 MB)
  char* ws = (char*)d_ws;
  _Float16* h0h = (_Float16*)ws;
  _Float16* h0l = (_Float16*)(ws + (size_t)M * H0 * 2);
  char* wp = ws + (size_t)M * H0 * 4;
  _Float16* W0hT = (_Float16*)wp;  wp += (size_t)D * H0 * 2;
  _Float16* W0lT = (_Float16*)wp;  wp += (size_t)D * H0 * 2;
  _Float16* W1hT = (_Float16*)wp;  wp += (size_t)H0 * H1 * 2;
  _Float16* W1lT = (_Float16*)wp;

  split_transpose_kernel<<<(D * H0 + 255) / 256, 256, 0, stream>>>(W0, W0hT, W0lT, D, H0);
  split_transpose_kernel<<<(H0 * H1 + 255) / 256, 256, 0, stream>>>(W1, W1hT, W1lT, H0, H1);

  // GEMM1: x(fp32, split in-loop) -> h0 split fp16 pair; grid = (M/128)*(H0/128) = 4096
  gemm_split_kernel<true, true><<<(M / 128) * (H0 / 128), 256, 0, stream>>>(
      x, nullptr, nullptr, W0hT, W0lT, b0, nullptr, h0h, h0l, D, H0);

  // fused GEMM2 + head: h0 pair -> out; grid = M/128 = 1024
  gemm2_head_kernel<<<M / 128, 512, 0, stream>>>(
      h0h, h0l, W1hT, W1lT, b1, W2, b2, out);
}